// Round 1
// baseline (393.164 us; speedup 1.0000x reference)
//
#include <hip/hip_runtime.h>
#include <hip/hip_bf16.h>
#include <math.h>

// Problem constants
#define B_  4
#define C_  64
#define H_  128
#define W_  128
#define HW_ (H_*W_)          // 16384
#define KK_ 9
#define GROUPS_ 32

// ---------------------------------------------------------------------------
// K0: transpose conv3x3 weights so inner loop reads contiguous per-(ci,pos)
// wt_off[(ci*9+pos)*18 + co] = w_off2[(co*64+ci)*9 + pos]
// wt_mask[(ci*9+pos)*9 + co] = w_mask2[(co*64+ci)*9 + pos]
// ---------------------------------------------------------------------------
__global__ void k0_wtrans(const float* __restrict__ w_off2,
                          const float* __restrict__ w_mask2,
                          float* __restrict__ wt_off,
                          float* __restrict__ wt_mask) {
    int i = blockIdx.x * 256 + threadIdx.x;
    if (i < 18 * 64 * 9) {
        int co = i / 576;
        int r  = i % 576;           // ci*9+pos
        wt_off[r * 18 + co] = w_off2[i];
    }
    if (i < 9 * 64 * 9) {
        int co = i / 576;
        int r  = i % 576;
        wt_mask[r * 9 + co] = w_mask2[i];
    }
}

// ---------------------------------------------------------------------------
// K1: fused dual 1x1 conv (t1 = x*W_off1^T, t2 = x*W_mask1^T) + NHWC transpose
// One thread per pixel. xv[64] register cache. Weights via scalar loads.
// ---------------------------------------------------------------------------
__global__ __launch_bounds__(256) void k1_conv1x1(const float* __restrict__ x,
                                                  const float* __restrict__ w1,
                                                  const float* __restrict__ w2,
                                                  float* __restrict__ t1,
                                                  float* __restrict__ t2,
                                                  float* __restrict__ xt) {
    int P  = blockIdx.x * 256 + threadIdx.x;   // 0..65535
    int b  = P >> 14;
    int hw = P & (HW_ - 1);

    const float* xp = x + (size_t)b * C_ * HW_ + hw;
    float xv[C_];
#pragma unroll
    for (int ci = 0; ci < C_; ci++) xv[ci] = xp[ci * HW_];

    // NHWC copy (free transpose)
    float4* xtp = (float4*)(xt + (size_t)P * C_);
#pragma unroll
    for (int j = 0; j < C_ / 4; j++)
        xtp[j] = make_float4(xv[4*j], xv[4*j+1], xv[4*j+2], xv[4*j+3]);

    float* o1 = t1 + (size_t)b * C_ * HW_ + hw;
    float* o2 = t2 + (size_t)b * C_ * HW_ + hw;
    for (int co = 0; co < C_; co++) {
        const float* wr1 = w1 + co * C_;   // uniform -> scalar loads
        const float* wr2 = w2 + co * C_;
        float a1 = 0.f, a2 = 0.f;
#pragma unroll
        for (int ci = 0; ci < C_; ci++) {
            a1 += wr1[ci] * xv[ci];
            a2 += wr2[ci] * xv[ci];
        }
        o1[co * HW_] = a1;
        o2[co * HW_] = a2;
    }
}

// ---------------------------------------------------------------------------
// K2: fused dual 3x3 conv (pad 1): off (18 ch) from t1, mask (9 ch, sigmoid)
// from t2. One thread per pixel, 27 accumulators, transposed scalar weights.
// ---------------------------------------------------------------------------
__global__ __launch_bounds__(256) void k2_conv3x3(const float* __restrict__ t1,
                                                  const float* __restrict__ t2,
                                                  const float* __restrict__ wt_off,
                                                  const float* __restrict__ wt_mask,
                                                  float* __restrict__ off,
                                                  float* __restrict__ mask) {
    int P  = blockIdx.x * 256 + threadIdx.x;
    int b  = P >> 14;
    int hw = P & (HW_ - 1);
    int h  = hw >> 7;
    int w  = hw & (W_ - 1);

    float ao[18];
    float am[9];
#pragma unroll
    for (int i = 0; i < 18; i++) ao[i] = 0.f;
#pragma unroll
    for (int i = 0; i < 9; i++) am[i] = 0.f;

    const float* p1 = t1 + (size_t)b * C_ * HW_;
    const float* p2 = t2 + (size_t)b * C_ * HW_;

    for (int pos = 0; pos < 9; pos++) {
        int dy = pos / 3 - 1, dx = pos % 3 - 1;
        int y = h + dy, xw = w + dx;
        if (y < 0 || y >= H_ || xw < 0 || xw >= W_) continue;  // zero pad
        int o = y * W_ + xw;
        for (int ci = 0; ci < C_; ci++) {
            float v1 = p1[ci * HW_ + o];
            float v2 = p2[ci * HW_ + o];
            const float* wo = wt_off  + (ci * 9 + pos) * 18;  // uniform -> s_load
            const float* wm = wt_mask + (ci * 9 + pos) * 9;
#pragma unroll
            for (int co = 0; co < 18; co++) ao[co] += wo[co] * v1;
#pragma unroll
            for (int co = 0; co < 9; co++)  am[co] += wm[co] * v2;
        }
    }

    float* offp  = off  + (size_t)b * 18 * HW_ + hw;
    float* maskp = mask + (size_t)b * 9  * HW_ + hw;
#pragma unroll
    for (int co = 0; co < 18; co++) offp[co * HW_] = ao[co];
#pragma unroll
    for (int co = 0; co < 9; co++)
        maskp[co * HW_] = 1.f / (1.f + expf(-am[co]));
}

// ---------------------------------------------------------------------------
// K3: deformable bilinear gather + einsum + bias -> out_pre (NCHW)
// 4 threads per pixel, 16 channels each. NHWC float4 gathers.
// ---------------------------------------------------------------------------
__global__ __launch_bounds__(256) void k3_deform(const float* __restrict__ xt,
                                                 const float* __restrict__ off,
                                                 const float* __restrict__ mask,
                                                 const float* __restrict__ weight,
                                                 const float* __restrict__ bias,
                                                 float* __restrict__ out_pre) {
    __shared__ float wl[C_ * KK_];
    __shared__ float bl[C_];
    for (int i = threadIdx.x; i < C_ * KK_; i += 256) wl[i] = weight[i];
    if (threadIdx.x < C_) bl[threadIdx.x] = bias[threadIdx.x];
    __syncthreads();

    int t     = blockIdx.x * 256 + threadIdx.x;
    int P     = t >> 2;           // pixel
    int chunk = t & 3;
    int c0    = chunk * 16;
    int b  = P >> 14;
    int hw = P & (HW_ - 1);
    int h  = hw >> 7;
    int w  = hw & (W_ - 1);

    float acc[16];
#pragma unroll
    for (int i = 0; i < 16; i++) acc[i] = 0.f;

    const float* offp = off  + (size_t)b * 18 * HW_ + hw;
    const float* mp   = mask + (size_t)b * 9  * HW_ + hw;
    const float* xb   = xt   + (size_t)b * HW_ * C_;

    for (int k = 0; k < 9; k++) {
        float mk   = mp[k * HW_];
        float offy = offp[(2 * k) * HW_];
        float offx = offp[(2 * k + 1) * HW_];
        float py = offy + (float)h + (float)(k / 3 - 1);
        float px = offx + (float)w + (float)(k % 3 - 1);
        float y0f = floorf(py), x0f = floorf(px);
        int y0 = (int)y0f, x0 = (int)x0f;
        int y1 = y0 + 1,   x1 = x0 + 1;
        float wy1 = py - y0f, wx1 = px - x0f;
        float wy0 = 1.f - wy1, wx0 = 1.f - wx1;
        bool vy0 = ((unsigned)y0 < (unsigned)H_);
        bool vy1 = ((unsigned)y1 < (unsigned)H_);
        bool vx0 = ((unsigned)x0 < (unsigned)W_);
        bool vx1 = ((unsigned)x1 < (unsigned)W_);
        int cy0 = min(max(y0, 0), H_ - 1);
        int cy1 = min(max(y1, 0), H_ - 1);
        int cx0 = min(max(x0, 0), W_ - 1);
        int cx1 = min(max(x1, 0), W_ - 1);
        float b00 = wy0 * wx0 * ((vy0 && vx0) ? mk : 0.f);
        float b01 = wy0 * wx1 * ((vy0 && vx1) ? mk : 0.f);
        float b10 = wy1 * wx0 * ((vy1 && vx0) ? mk : 0.f);
        float b11 = wy1 * wx1 * ((vy1 && vx1) ? mk : 0.f);

        const float* p00 = xb + ((size_t)cy0 * W_ + cx0) * C_ + c0;
        const float* p01 = xb + ((size_t)cy0 * W_ + cx1) * C_ + c0;
        const float* p10 = xb + ((size_t)cy1 * W_ + cx0) * C_ + c0;
        const float* p11 = xb + ((size_t)cy1 * W_ + cx1) * C_ + c0;

#pragma unroll
        for (int q = 0; q < 4; q++) {
            float4 v00 = *(const float4*)(p00 + 4 * q);
            float4 v01 = *(const float4*)(p01 + 4 * q);
            float4 v10 = *(const float4*)(p10 + 4 * q);
            float4 v11 = *(const float4*)(p11 + 4 * q);
            float sx = b00 * v00.x + b01 * v01.x + b10 * v10.x + b11 * v11.x;
            float sy = b00 * v00.y + b01 * v01.y + b10 * v10.y + b11 * v11.y;
            float sz = b00 * v00.z + b01 * v01.z + b10 * v10.z + b11 * v11.z;
            float sw = b00 * v00.w + b01 * v01.w + b10 * v10.w + b11 * v11.w;
            acc[4*q+0] += wl[(c0 + 4*q + 0) * 9 + k] * sx;
            acc[4*q+1] += wl[(c0 + 4*q + 1) * 9 + k] * sy;
            acc[4*q+2] += wl[(c0 + 4*q + 2) * 9 + k] * sz;
            acc[4*q+3] += wl[(c0 + 4*q + 3) * 9 + k] * sw;
        }
    }

    float* op = out_pre + ((size_t)b * C_ + c0) * HW_ + hw;
#pragma unroll
    for (int c = 0; c < 16; c++) op[c * HW_] = acc[c] + bl[c0 + c];
}

// ---------------------------------------------------------------------------
// K4: per-(b,group) mean / rstd. One block per (b*32+g); 2*HW contiguous floats
// ---------------------------------------------------------------------------
__global__ __launch_bounds__(256) void k4_stats(const float* __restrict__ out_pre,
                                                float* __restrict__ stats) {
    int bg = blockIdx.x;   // 0..127
    const float4* p = (const float4*)(out_pre + (size_t)bg * 2 * HW_);
    float s = 0.f, ss = 0.f;
    for (int i = threadIdx.x; i < 2 * HW_ / 4; i += 256) {
        float4 v = p[i];
        s  += v.x + v.y + v.z + v.w;
        ss += v.x * v.x + v.y * v.y + v.z * v.z + v.w * v.w;
    }
#pragma unroll
    for (int m = 1; m < 64; m <<= 1) {
        s  += __shfl_xor(s, m);
        ss += __shfl_xor(ss, m);
    }
    __shared__ float ls[8];
    int lane = threadIdx.x & 63, wid = threadIdx.x >> 6;
    if (lane == 0) { ls[wid] = s; ls[4 + wid] = ss; }
    __syncthreads();
    if (threadIdx.x == 0) {
        float S  = ls[0] + ls[1] + ls[2] + ls[3];
        float SS = ls[4] + ls[5] + ls[6] + ls[7];
        const float inv = 1.f / (2.f * HW_);
        float mean = S * inv;
        float var  = SS * inv - mean * mean;
        stats[bg * 2]     = mean;
        stats[bg * 2 + 1] = rsqrtf(var + 1e-5f);
    }
}

// ---------------------------------------------------------------------------
// K5: normalize + gamma/beta + exact GELU -> d_out (float4)
// ---------------------------------------------------------------------------
__global__ __launch_bounds__(256) void k5_norm_gelu(const float* __restrict__ out_pre,
                                                    const float* __restrict__ stats,
                                                    const float* __restrict__ gamma,
                                                    const float* __restrict__ beta,
                                                    float* __restrict__ out) {
    int i = blockIdx.x * 256 + threadIdx.x;       // float4 index, 0..1048575
    int e = i << 2;
    int c = (e >> 14) & (C_ - 1);
    int b = e >> 20;
    int bg = b * GROUPS_ + (c >> 1);
    float mean = stats[bg * 2];
    float rstd = stats[bg * 2 + 1];
    float ga = gamma[c] * rstd;
    float be = beta[c] - mean * ga;
    float4 v = ((const float4*)out_pre)[i];
    float4 r;
    float t;
    t = v.x * ga + be; r.x = 0.5f * t * (1.f + erff(t * 0.70710678118654752f));
    t = v.y * ga + be; r.y = 0.5f * t * (1.f + erff(t * 0.70710678118654752f));
    t = v.z * ga + be; r.z = 0.5f * t * (1.f + erff(t * 0.70710678118654752f));
    t = v.w * ga + be; r.w = 0.5f * t * (1.f + erff(t * 0.70710678118654752f));
    ((float4*)out)[i] = r;
}

// ---------------------------------------------------------------------------
extern "C" void kernel_launch(void* const* d_in, const int* in_sizes, int n_in,
                              void* d_out, int out_size, void* d_ws, size_t ws_size,
                              hipStream_t stream) {
    const float* x       = (const float*)d_in[0];
    const float* w_off1  = (const float*)d_in[1];
    const float* w_off2  = (const float*)d_in[2];
    const float* w_mask1 = (const float*)d_in[3];
    const float* w_mask2 = (const float*)d_in[4];
    const float* weight  = (const float*)d_in[5];
    const float* bias    = (const float*)d_in[6];
    const float* gamma   = (const float*)d_in[7];
    const float* beta    = (const float*)d_in[8];
    float* out = (float*)d_out;

    // Workspace layout (floats). out_pre aliases t1 (t1 dead after K2).
    constexpr size_t NX = (size_t)B_ * C_ * HW_;        // 4,194,304
    float* ws      = (float*)d_ws;
    float* wt_off  = ws;                                 // 10368
    float* wt_mask = wt_off + 10368;                     // 5184
    float* t1      = wt_mask + 5184;                     // NX  (aliased by out_pre)
    float* t2      = t1 + NX;                            // NX
    float* xt      = t2 + NX;                            // NX
    float* offb    = xt + NX;                            // B*18*HW
    float* maskb   = offb + (size_t)B_ * 18 * HW_;       // B*9*HW
    float* stats   = maskb + (size_t)B_ * 9 * HW_;       // 256
    float* out_pre = t1;

    int npix = B_ * HW_;                                 // 65536

    hipLaunchKernelGGL(k0_wtrans, dim3((18 * 64 * 9 + 255) / 256), dim3(256), 0, stream,
                       w_off2, w_mask2, wt_off, wt_mask);
    hipLaunchKernelGGL(k1_conv1x1, dim3(npix / 256), dim3(256), 0, stream,
                       x, w_off1, w_mask1, t1, t2, xt);
    hipLaunchKernelGGL(k2_conv3x3, dim3(npix / 256), dim3(256), 0, stream,
                       t1, t2, wt_off, wt_mask, offb, maskb);
    hipLaunchKernelGGL(k3_deform, dim3(npix * 4 / 256), dim3(256), 0, stream,
                       xt, offb, maskb, weight, bias, out_pre);
    hipLaunchKernelGGL(k4_stats, dim3(B_ * GROUPS_), dim3(256), 0, stream,
                       out_pre, stats);
    hipLaunchKernelGGL(k5_norm_gelu, dim3((int)(NX / 4 / 256)), dim3(256), 0, stream,
                       out_pre, stats, gamma, beta, out);
}

// Round 2
// 320.954 us; speedup vs baseline: 1.2250x; 1.2250x over previous
//
#include <hip/hip_runtime.h>
#include <hip/hip_bf16.h>
#include <math.h>

// Problem constants
#define B_  4
#define C_  64
#define H_  128
#define W_  128
#define HW_ (H_*W_)          // 16384
#define KK_ 9
#define GROUPS_ 32

// ---------------------------------------------------------------------------
// K0: transpose conv3x3 weights so inner loop reads contiguous per-(ci,pos)
// wt_off[(ci*9+pos)*18 + co] = w_off2[(co*64+ci)*9 + pos]
// wt_mask[(ci*9+pos)*9 + co] = w_mask2[(co*64+ci)*9 + pos]
// ---------------------------------------------------------------------------
__global__ void k0_wtrans(const float* __restrict__ w_off2,
                          const float* __restrict__ w_mask2,
                          float* __restrict__ wt_off,
                          float* __restrict__ wt_mask) {
    int i = blockIdx.x * 256 + threadIdx.x;
    if (i < 18 * 64 * 9) {
        int co = i / 576;
        int r  = i % 576;           // ci*9+pos
        wt_off[r * 18 + co] = w_off2[i];
    }
    if (i < 9 * 64 * 9) {
        int co = i / 576;
        int r  = i % 576;
        wt_mask[r * 9 + co] = w_mask2[i];
    }
}

// ---------------------------------------------------------------------------
// K1: fused dual 1x1 conv + NHWC transpose.
// Block = 4 waves over the SAME 64 pixels; wave w owns co chunk [16w,16w+16).
// co is wave-uniform -> weight reads compile to scalar loads.
// Grid 1024 blocks -> 16 waves/CU (was 4).
// ---------------------------------------------------------------------------
__global__ __launch_bounds__(256) void k1_conv1x1(const float* __restrict__ x,
                                                  const float* __restrict__ w1,
                                                  const float* __restrict__ w2,
                                                  float* __restrict__ t1,
                                                  float* __restrict__ t2,
                                                  float* __restrict__ xt) {
    int lane = threadIdx.x & 63;
    int wave = threadIdx.x >> 6;          // 0..3
    int c0   = wave * 16;
    int P    = blockIdx.x * 64 + lane;    // pixel, 0..65535
    int b    = P >> 14;
    int hw   = P & (HW_ - 1);

    const float* xp = x + (size_t)b * C_ * HW_ + hw;
    float xv[C_];
#pragma unroll
    for (int ci = 0; ci < C_; ci++) xv[ci] = xp[ci * HW_];

    // NHWC transpose: each wave writes its own 16-channel slice of this pixel
    float4* xtp = (float4*)(xt + (size_t)P * C_ + c0);
#pragma unroll
    for (int j = 0; j < 4; j++)
        xtp[j] = make_float4(xv[c0 + 4*j], xv[c0 + 4*j + 1],
                             xv[c0 + 4*j + 2], xv[c0 + 4*j + 3]);

    float* o1 = t1 + (size_t)b * C_ * HW_ + hw;
    float* o2 = t2 + (size_t)b * C_ * HW_ + hw;
#pragma unroll 4
    for (int cc = 0; cc < 16; cc++) {
        int co = c0 + cc;                  // wave-uniform
        const float* wr1 = w1 + co * C_;   // -> s_load
        const float* wr2 = w2 + co * C_;
        float a1 = 0.f, a2 = 0.f;
#pragma unroll
        for (int ci = 0; ci < C_; ci++) {
            a1 += wr1[ci] * xv[ci];
            a2 += wr2[ci] * xv[ci];
        }
        o1[co * HW_] = a1;
        o2[co * HW_] = a2;
    }
}

// ---------------------------------------------------------------------------
// K2: fused dual 3x3 conv (pad 1). Block = 4 waves, 128 pixels:
//   wave 0,1 -> off conv (18 ch) on t1 for pixels [0,64),[64,128)
//   wave 2,3 -> mask conv (9 ch, sigmoid) on t2
// Weight rows wave-uniform -> scalar loads. Grid 512 blocks -> 8 waves/CU.
// ---------------------------------------------------------------------------
__global__ __launch_bounds__(256) void k2_conv3x3(const float* __restrict__ t1,
                                                  const float* __restrict__ t2,
                                                  const float* __restrict__ wt_off,
                                                  const float* __restrict__ wt_mask,
                                                  float* __restrict__ off,
                                                  float* __restrict__ mask) {
    int lane = threadIdx.x & 63;
    int wave = threadIdx.x >> 6;
    int half = wave & 1;
    int isMask = wave >> 1;

    int P  = blockIdx.x * 128 + half * 64 + lane;
    int b  = P >> 14;
    int hw = P & (HW_ - 1);
    int h  = hw >> 7;
    int w  = hw & (W_ - 1);

    if (!isMask) {
        float ao[18];
#pragma unroll
        for (int i = 0; i < 18; i++) ao[i] = 0.f;
        const float* p1 = t1 + (size_t)b * C_ * HW_;
#pragma unroll
        for (int pos = 0; pos < 9; pos++) {
            int dy = pos / 3 - 1, dx = pos % 3 - 1;
            int y = h + dy, xw = w + dx;
            if (y < 0 || y >= H_ || xw < 0 || xw >= W_) continue;  // zero pad
            const float* pp = p1 + y * W_ + xw;
#pragma unroll 4
            for (int ci = 0; ci < C_; ci++) {
                float v1 = pp[ci * HW_];
                const float* wo = wt_off + (ci * 9 + pos) * 18;  // uniform
#pragma unroll
                for (int co = 0; co < 18; co++) ao[co] += wo[co] * v1;
            }
        }
        float* offp = off + (size_t)b * 18 * HW_ + hw;
#pragma unroll
        for (int co = 0; co < 18; co++) offp[co * HW_] = ao[co];
    } else {
        float am[9];
#pragma unroll
        for (int i = 0; i < 9; i++) am[i] = 0.f;
        const float* p2 = t2 + (size_t)b * C_ * HW_;
#pragma unroll
        for (int pos = 0; pos < 9; pos++) {
            int dy = pos / 3 - 1, dx = pos % 3 - 1;
            int y = h + dy, xw = w + dx;
            if (y < 0 || y >= H_ || xw < 0 || xw >= W_) continue;
            const float* pp = p2 + y * W_ + xw;
#pragma unroll 4
            for (int ci = 0; ci < C_; ci++) {
                float v2 = pp[ci * HW_];
                const float* wm = wt_mask + (ci * 9 + pos) * 9;  // uniform
#pragma unroll
                for (int co = 0; co < 9; co++) am[co] += wm[co] * v2;
            }
        }
        float* maskp = mask + (size_t)b * 9 * HW_ + hw;
#pragma unroll
        for (int co = 0; co < 9; co++)
            maskp[co * HW_] = 1.f / (1.f + expf(-am[co]));
    }
}

// ---------------------------------------------------------------------------
// K3: deformable bilinear gather + einsum + bias -> out_pre (NCHW)
// 4 threads per pixel, 16 channels each. NHWC float4 gathers.
// ---------------------------------------------------------------------------
__global__ __launch_bounds__(256) void k3_deform(const float* __restrict__ xt,
                                                 const float* __restrict__ off,
                                                 const float* __restrict__ mask,
                                                 const float* __restrict__ weight,
                                                 const float* __restrict__ bias,
                                                 float* __restrict__ out_pre) {
    __shared__ float wl[C_ * KK_];
    __shared__ float bl[C_];
    for (int i = threadIdx.x; i < C_ * KK_; i += 256) wl[i] = weight[i];
    if (threadIdx.x < C_) bl[threadIdx.x] = bias[threadIdx.x];
    __syncthreads();

    int t     = blockIdx.x * 256 + threadIdx.x;
    int P     = t >> 2;           // pixel
    int chunk = t & 3;
    int c0    = chunk * 16;
    int b  = P >> 14;
    int hw = P & (HW_ - 1);
    int h  = hw >> 7;
    int w  = hw & (W_ - 1);

    float acc[16];
#pragma unroll
    for (int i = 0; i < 16; i++) acc[i] = 0.f;

    const float* offp = off  + (size_t)b * 18 * HW_ + hw;
    const float* mp   = mask + (size_t)b * 9  * HW_ + hw;
    const float* xb   = xt   + (size_t)b * HW_ * C_;

    for (int k = 0; k < 9; k++) {
        float mk   = mp[k * HW_];
        float offy = offp[(2 * k) * HW_];
        float offx = offp[(2 * k + 1) * HW_];
        float py = offy + (float)h + (float)(k / 3 - 1);
        float px = offx + (float)w + (float)(k % 3 - 1);
        float y0f = floorf(py), x0f = floorf(px);
        int y0 = (int)y0f, x0 = (int)x0f;
        int y1 = y0 + 1,   x1 = x0 + 1;
        float wy1 = py - y0f, wx1 = px - x0f;
        float wy0 = 1.f - wy1, wx0 = 1.f - wx1;
        bool vy0 = ((unsigned)y0 < (unsigned)H_);
        bool vy1 = ((unsigned)y1 < (unsigned)H_);
        bool vx0 = ((unsigned)x0 < (unsigned)W_);
        bool vx1 = ((unsigned)x1 < (unsigned)W_);
        int cy0 = min(max(y0, 0), H_ - 1);
        int cy1 = min(max(y1, 0), H_ - 1);
        int cx0 = min(max(x0, 0), W_ - 1);
        int cx1 = min(max(x1, 0), W_ - 1);
        float b00 = wy0 * wx0 * ((vy0 && vx0) ? mk : 0.f);
        float b01 = wy0 * wx1 * ((vy0 && vx1) ? mk : 0.f);
        float b10 = wy1 * wx0 * ((vy1 && vx0) ? mk : 0.f);
        float b11 = wy1 * wx1 * ((vy1 && vx1) ? mk : 0.f);

        const float* p00 = xb + ((size_t)cy0 * W_ + cx0) * C_ + c0;
        const float* p01 = xb + ((size_t)cy0 * W_ + cx1) * C_ + c0;
        const float* p10 = xb + ((size_t)cy1 * W_ + cx0) * C_ + c0;
        const float* p11 = xb + ((size_t)cy1 * W_ + cx1) * C_ + c0;

#pragma unroll
        for (int q = 0; q < 4; q++) {
            float4 v00 = *(const float4*)(p00 + 4 * q);
            float4 v01 = *(const float4*)(p01 + 4 * q);
            float4 v10 = *(const float4*)(p10 + 4 * q);
            float4 v11 = *(const float4*)(p11 + 4 * q);
            float sx = b00 * v00.x + b01 * v01.x + b10 * v10.x + b11 * v11.x;
            float sy = b00 * v00.y + b01 * v01.y + b10 * v10.y + b11 * v11.y;
            float sz = b00 * v00.z + b01 * v01.z + b10 * v10.z + b11 * v11.z;
            float sw = b00 * v00.w + b01 * v01.w + b10 * v10.w + b11 * v11.w;
            acc[4*q+0] += wl[(c0 + 4*q + 0) * 9 + k] * sx;
            acc[4*q+1] += wl[(c0 + 4*q + 1) * 9 + k] * sy;
            acc[4*q+2] += wl[(c0 + 4*q + 2) * 9 + k] * sz;
            acc[4*q+3] += wl[(c0 + 4*q + 3) * 9 + k] * sw;
        }
    }

    float* op = out_pre + ((size_t)b * C_ + c0) * HW_ + hw;
#pragma unroll
    for (int c = 0; c < 16; c++) op[c * HW_] = acc[c] + bl[c0 + c];
}

// ---------------------------------------------------------------------------
// K4: per-(b,group) mean / rstd. One block of 1024 threads per (b*32+g).
// 128 blocks x 16 waves -> 8 waves/CU (was 2).
// ---------------------------------------------------------------------------
__global__ __launch_bounds__(1024) void k4_stats(const float* __restrict__ out_pre,
                                                 float* __restrict__ stats) {
    int bg = blockIdx.x;   // 0..127
    const float4* p = (const float4*)(out_pre + (size_t)bg * 2 * HW_);
    float s = 0.f, ss = 0.f;
    for (int i = threadIdx.x; i < 2 * HW_ / 4; i += 1024) {
        float4 v = p[i];
        s  += v.x + v.y + v.z + v.w;
        ss += v.x * v.x + v.y * v.y + v.z * v.z + v.w * v.w;
    }
#pragma unroll
    for (int m = 1; m < 64; m <<= 1) {
        s  += __shfl_xor(s, m);
        ss += __shfl_xor(ss, m);
    }
    __shared__ float ls[32];
    int lane = threadIdx.x & 63, wid = threadIdx.x >> 6;   // 16 waves
    if (lane == 0) { ls[wid] = s; ls[16 + wid] = ss; }
    __syncthreads();
    if (threadIdx.x == 0) {
        float S = 0.f, SS = 0.f;
#pragma unroll
        for (int i = 0; i < 16; i++) { S += ls[i]; SS += ls[16 + i]; }
        const float inv = 1.f / (2.f * HW_);
        float mean = S * inv;
        float var  = SS * inv - mean * mean;
        stats[bg * 2]     = mean;
        stats[bg * 2 + 1] = rsqrtf(var + 1e-5f);
    }
}

// ---------------------------------------------------------------------------
// K5: normalize + gamma/beta + exact GELU -> d_out (float4)
// ---------------------------------------------------------------------------
__global__ __launch_bounds__(256) void k5_norm_gelu(const float* __restrict__ out_pre,
                                                    const float* __restrict__ stats,
                                                    const float* __restrict__ gamma,
                                                    const float* __restrict__ beta,
                                                    float* __restrict__ out) {
    int i = blockIdx.x * 256 + threadIdx.x;       // float4 index
    int e = i << 2;
    int c = (e >> 14) & (C_ - 1);
    int b = e >> 20;
    int bg = b * GROUPS_ + (c >> 1);
    float mean = stats[bg * 2];
    float rstd = stats[bg * 2 + 1];
    float ga = gamma[c] * rstd;
    float be = beta[c] - mean * ga;
    float4 v = ((const float4*)out_pre)[i];
    float4 r;
    float t;
    t = v.x * ga + be; r.x = 0.5f * t * (1.f + erff(t * 0.70710678118654752f));
    t = v.y * ga + be; r.y = 0.5f * t * (1.f + erff(t * 0.70710678118654752f));
    t = v.z * ga + be; r.z = 0.5f * t * (1.f + erff(t * 0.70710678118654752f));
    t = v.w * ga + be; r.w = 0.5f * t * (1.f + erff(t * 0.70710678118654752f));
    ((float4*)out)[i] = r;
}

// ---------------------------------------------------------------------------
extern "C" void kernel_launch(void* const* d_in, const int* in_sizes, int n_in,
                              void* d_out, int out_size, void* d_ws, size_t ws_size,
                              hipStream_t stream) {
    const float* x       = (const float*)d_in[0];
    const float* w_off1  = (const float*)d_in[1];
    const float* w_off2  = (const float*)d_in[2];
    const float* w_mask1 = (const float*)d_in[3];
    const float* w_mask2 = (const float*)d_in[4];
    const float* weight  = (const float*)d_in[5];
    const float* bias    = (const float*)d_in[6];
    const float* gamma   = (const float*)d_in[7];
    const float* beta    = (const float*)d_in[8];
    float* out = (float*)d_out;

    // Workspace layout (floats). out_pre aliases t1 (t1 dead after K2).
    constexpr size_t NX = (size_t)B_ * C_ * HW_;        // 4,194,304
    float* ws      = (float*)d_ws;
    float* wt_off  = ws;                                 // 10368
    float* wt_mask = wt_off + 10368;                     // 5184
    float* t1      = wt_mask + 5184;                     // NX  (aliased by out_pre)
    float* t2      = t1 + NX;                            // NX
    float* xt      = t2 + NX;                            // NX
    float* offb    = xt + NX;                            // B*18*HW
    float* maskb   = offb + (size_t)B_ * 18 * HW_;       // B*9*HW
    float* stats   = maskb + (size_t)B_ * 9 * HW_;       // 256
    float* out_pre = t1;

    int npix = B_ * HW_;                                 // 65536

    hipLaunchKernelGGL(k0_wtrans, dim3((18 * 64 * 9 + 255) / 256), dim3(256), 0, stream,
                       w_off2, w_mask2, wt_off, wt_mask);
    hipLaunchKernelGGL(k1_conv1x1, dim3(npix / 64), dim3(256), 0, stream,
                       x, w_off1, w_mask1, t1, t2, xt);
    hipLaunchKernelGGL(k2_conv3x3, dim3(npix / 128), dim3(256), 0, stream,
                       t1, t2, wt_off, wt_mask, offb, maskb);
    hipLaunchKernelGGL(k3_deform, dim3(npix * 4 / 256), dim3(256), 0, stream,
                       xt, offb, maskb, weight, bias, out_pre);
    hipLaunchKernelGGL(k4_stats, dim3(B_ * GROUPS_), dim3(1024), 0, stream,
                       out_pre, stats);
    hipLaunchKernelGGL(k5_norm_gelu, dim3((int)(NX / 4 / 256)), dim3(256), 0, stream,
                       out_pre, stats, gamma, beta, out);
}

// Round 3
// 215.697 us; speedup vs baseline: 1.8228x; 1.4880x over previous
//
#include <hip/hip_runtime.h>
#include <math.h>

#define B_  4
#define C_  64
#define H_  128
#define W_  128
#define HW_ (H_*W_)          // 16384
#define NPIX_ (B_*HW_)       // 65536
#define GROUPS_ 32

typedef __attribute__((ext_vector_type(8))) short short8;
typedef __attribute__((ext_vector_type(4))) float f32x4;

__device__ inline short f2bf_rne(float f) {
    unsigned u = __float_as_uint(f);
    unsigned r = (u + 0x7FFFu + ((u >> 16) & 1u)) >> 16;
    return (short)r;
}
__device__ inline float bf2f(short h) {
    return __uint_as_float(((unsigned)(unsigned short)h) << 16);
}

// ---------------------------------------------------------------------------
// K0: weight prep.
//  w1cat[128][64] bf16 hi/lo: rows 0-63 = w_off1, 64-127 = w_mask1
//  wo  [32][9][64] bf16 hi/lo: wo[cout][pos][ci] = w_off2[cout][ci][pos], rows>=18 zero
//  wm  [16][9][64] bf16 hi/lo: same from w_mask2, rows>=9 zero
// ---------------------------------------------------------------------------
__global__ void k0_prep(const float* __restrict__ w_off1, const float* __restrict__ w_mask1,
                        const float* __restrict__ w_off2, const float* __restrict__ w_mask2,
                        short* __restrict__ w1_hi, short* __restrict__ w1_lo,
                        short* __restrict__ wo_hi, short* __restrict__ wo_lo,
                        short* __restrict__ wm_hi, short* __restrict__ wm_lo) {
    int i = blockIdx.x * 256 + threadIdx.x;
    if (i < 8192) {
        int co = i >> 6, ci = i & 63;
        float v = (co < 64) ? w_off1[co * 64 + ci] : w_mask1[(co - 64) * 64 + ci];
        short h = f2bf_rne(v);
        w1_hi[i] = h;
        w1_lo[i] = f2bf_rne(v - bf2f(h));
    }
    if (i < 32 * 576) {
        int cout = i / 576, r = i % 576;
        int pos = r >> 6, ci = r & 63;
        float v = (cout < 18) ? w_off2[(cout * 64 + ci) * 9 + pos] : 0.f;
        short h = f2bf_rne(v);
        wo_hi[i] = h;
        wo_lo[i] = f2bf_rne(v - bf2f(h));
    }
    if (i < 16 * 576) {
        int cout = i / 576, r = i % 576;
        int pos = r >> 6, ci = r & 63;
        float v = (cout < 9) ? w_mask2[(cout * 64 + ci) * 9 + pos] : 0.f;
        short h = f2bf_rne(v);
        wm_hi[i] = h;
        wm_lo[i] = f2bf_rne(v - bf2f(h));
    }
}

// ---------------------------------------------------------------------------
// K1: dual 1x1 conv via MFMA. D[pix][co128] = bf16(x)[pix][ci] * (Whi+Wlo)[ci][co]
// Block = 128 pixels (one image row), wave w owns 32 pixels (2 M-tiles).
// A-frags direct from NCHW x (coalesced); emits xt (NHWC fp32) from the same
// registers; t1/t2 written NHWC bf16 for k2.
// ---------------------------------------------------------------------------
__global__ __launch_bounds__(256) void k1_mfma(const float* __restrict__ x,
                                               const short* __restrict__ w1_hi,
                                               const short* __restrict__ w1_lo,
                                               short* __restrict__ t1b,
                                               short* __restrict__ t2b,
                                               float* __restrict__ xt) {
    int l   = threadIdx.x & 63;
    int wv  = threadIdx.x >> 6;
    int row = l >> 4, col = l & 15;
    int p0  = blockIdx.x * 128 + wv * 32;     // wave's pixel base
    int b   = p0 >> 14;
    int hw  = p0 & (HW_ - 1);
    const float* xb = x + (size_t)b * C_ * HW_ + hw;

    short8 afr[2][2];
#pragma unroll
    for (int mt = 0; mt < 2; mt++) {
        int pl = mt * 16 + col;               // lane's local pixel (A row m)
#pragma unroll
        for (int kb = 0; kb < 2; kb++) {
            int ci0 = kb * 32 + row * 8;      // A col k base
            float xv[8];
#pragma unroll
            for (int j = 0; j < 8; j++) xv[j] = xb[(ci0 + j) * HW_ + pl];
            float4* xp = (float4*)(xt + ((size_t)(p0 + pl)) * 64 + ci0);
            xp[0] = make_float4(xv[0], xv[1], xv[2], xv[3]);
            xp[1] = make_float4(xv[4], xv[5], xv[6], xv[7]);
            short8 a;
#pragma unroll
            for (int j = 0; j < 8; j++) a[j] = f2bf_rne(xv[j]);
            afr[mt][kb] = a;
        }
    }

    for (int nt = 0; nt < 8; nt++) {
        int co = nt * 16 + col;               // B col n
        union { uint4 u; short8 s; } cv;
        short8 bh[2], bl[2];
        const short* ph = w1_hi + (size_t)co * 64 + row * 8;
        const short* pl_ = w1_lo + (size_t)co * 64 + row * 8;
        cv.u = *(const uint4*)(ph);        bh[0] = cv.s;
        cv.u = *(const uint4*)(ph + 32);   bh[1] = cv.s;
        cv.u = *(const uint4*)(pl_);       bl[0] = cv.s;
        cv.u = *(const uint4*)(pl_ + 32);  bl[1] = cv.s;
        short* tgt = (co < 64) ? t1b : t2b;
        int c6 = co & 63;
#pragma unroll
        for (int mt = 0; mt < 2; mt++) {
            f32x4 acc = {0.f, 0.f, 0.f, 0.f};
            acc = __builtin_amdgcn_mfma_f32_16x16x32_bf16(afr[mt][0], bh[0], acc, 0, 0, 0);
            acc = __builtin_amdgcn_mfma_f32_16x16x32_bf16(afr[mt][0], bl[0], acc, 0, 0, 0);
            acc = __builtin_amdgcn_mfma_f32_16x16x32_bf16(afr[mt][1], bh[1], acc, 0, 0, 0);
            acc = __builtin_amdgcn_mfma_f32_16x16x32_bf16(afr[mt][1], bl[1], acc, 0, 0, 0);
#pragma unroll
            for (int r = 0; r < 4; r++) {
                int p = p0 + mt * 16 + row * 4 + r;
                tgt[(size_t)p * 64 + c6] = f2bf_rne(acc[r]);
            }
        }
    }
}

// ---------------------------------------------------------------------------
// K2: dual 3x3 conv via MFMA, K = 9pos x 64ci = 576 (pos-major).
// D[pix][cout]: off cout 0-17 (2 N-tiles), mask cout 0-8 (1 N-tile, sigmoid).
// A-frags = 16B contiguous loads from NHWC bf16 t1b/t2b at shifted pixels,
// zero-predicated at image borders. Output row offmask[pix][32]:
// [0..17]=off, [18..26]=mask.
// ---------------------------------------------------------------------------
__global__ __launch_bounds__(256) void k2_mfma(const short* __restrict__ t1b,
                                               const short* __restrict__ t2b,
                                               const short* __restrict__ wo_hi,
                                               const short* __restrict__ wo_lo,
                                               const short* __restrict__ wm_hi,
                                               const short* __restrict__ wm_lo,
                                               float* __restrict__ offmask) {
    int l   = threadIdx.x & 63;
    int wv  = threadIdx.x >> 6;
    int row = l >> 4, col = l & 15;
    int blk = blockIdx.x;
    int h   = blk & 127;                       // image row (blocks = one row each)
    int p0  = blk * 128;                       // global pixel base of this row
    int w0  = wv * 32;                         // wave's w-range [w0, w0+32)

    f32x4 aco[2][2] = {{{0.f,0.f,0.f,0.f},{0.f,0.f,0.f,0.f}},
                       {{0.f,0.f,0.f,0.f},{0.f,0.f,0.f,0.f}}};
    f32x4 acm[2]    = {{0.f,0.f,0.f,0.f},{0.f,0.f,0.f,0.f}};

    for (int kb = 0; kb < 18; kb++) {
        int pos = kb >> 1;
        int dy = pos / 3 - 1, dx = pos % 3 - 1;
        int ci0 = (kb & 1) * 32 + row * 8;
        int koff = pos * 64 + ci0;
        union { uint4 u; short8 s; } cv;
        short8 boh0, boh1, bol0, bol1, bmh, bml;
        cv.u = *(const uint4*)(wo_hi + (size_t)col * 576 + koff);        boh0 = cv.s;
        cv.u = *(const uint4*)(wo_hi + (size_t)(col + 16) * 576 + koff); boh1 = cv.s;
        cv.u = *(const uint4*)(wo_lo + (size_t)col * 576 + koff);        bol0 = cv.s;
        cv.u = *(const uint4*)(wo_lo + (size_t)(col + 16) * 576 + koff); bol1 = cv.s;
        cv.u = *(const uint4*)(wm_hi + (size_t)col * 576 + koff);        bmh  = cv.s;
        cv.u = *(const uint4*)(wm_lo + (size_t)col * 576 + koff);        bml  = cv.s;
#pragma unroll
        for (int mt = 0; mt < 2; mt++) {
            int w = w0 + mt * 16 + col;
            bool valid = ((unsigned)(h + dy) < 128u) && ((unsigned)(w + dx) < 128u);
            int ps = p0 + w + dy * 128 + dx;    // shifted global pixel
            short8 a1 = {0,0,0,0,0,0,0,0};
            short8 a2 = {0,0,0,0,0,0,0,0};
            if (valid) {
                cv.u = *(const uint4*)(t1b + (size_t)ps * 64 + ci0); a1 = cv.s;
                cv.u = *(const uint4*)(t2b + (size_t)ps * 64 + ci0); a2 = cv.s;
            }
            aco[mt][0] = __builtin_amdgcn_mfma_f32_16x16x32_bf16(a1, boh0, aco[mt][0], 0, 0, 0);
            aco[mt][0] = __builtin_amdgcn_mfma_f32_16x16x32_bf16(a1, bol0, aco[mt][0], 0, 0, 0);
            aco[mt][1] = __builtin_amdgcn_mfma_f32_16x16x32_bf16(a1, boh1, aco[mt][1], 0, 0, 0);
            aco[mt][1] = __builtin_amdgcn_mfma_f32_16x16x32_bf16(a1, bol1, aco[mt][1], 0, 0, 0);
            acm[mt]    = __builtin_amdgcn_mfma_f32_16x16x32_bf16(a2, bmh,  acm[mt],    0, 0, 0);
            acm[mt]    = __builtin_amdgcn_mfma_f32_16x16x32_bf16(a2, bml,  acm[mt],    0, 0, 0);
        }
    }

#pragma unroll
    for (int mt = 0; mt < 2; mt++) {
#pragma unroll
        for (int r = 0; r < 4; r++) {
            int p = p0 + w0 + mt * 16 + row * 4 + r;
            float* om = offmask + (size_t)p * 32;
            om[col] = aco[mt][0][r];
            if (col < 2) om[16 + col] = aco[mt][1][r];
            if (col < 9) om[18 + col] = 1.f / (1.f + expf(-acm[mt][r]));
        }
    }
}

// ---------------------------------------------------------------------------
// K3: deformable bilinear gather + einsum + bias -> out_pre (NCHW)
// 4 threads per pixel, 16 channels each. NHWC float4 gathers; per-pixel
// off/mask now one contiguous 128B row.
// ---------------------------------------------------------------------------
__global__ __launch_bounds__(256) void k3_deform(const float* __restrict__ xt,
                                                 const float* __restrict__ offmask,
                                                 const float* __restrict__ weight,
                                                 const float* __restrict__ bias,
                                                 float* __restrict__ out_pre) {
    __shared__ float wl[C_ * 9];
    __shared__ float bl[C_];
    for (int i = threadIdx.x; i < C_ * 9; i += 256) wl[i] = weight[i];
    if (threadIdx.x < C_) bl[threadIdx.x] = bias[threadIdx.x];
    __syncthreads();

    int t     = blockIdx.x * 256 + threadIdx.x;
    int P     = t >> 2;
    int chunk = t & 3;
    int c0    = chunk * 16;
    int b  = P >> 14;
    int hw = P & (HW_ - 1);
    int h  = hw >> 7;
    int w  = hw & (W_ - 1);

    float acc[16];
#pragma unroll
    for (int i = 0; i < 16; i++) acc[i] = 0.f;

    const float* po = offmask + (size_t)P * 32;
    const float* xb = xt + (size_t)b * HW_ * C_;

    for (int k = 0; k < 9; k++) {
        float offy = po[2 * k];
        float offx = po[2 * k + 1];
        float mk   = po[18 + k];
        float py = offy + (float)h + (float)(k / 3 - 1);
        float px = offx + (float)w + (float)(k % 3 - 1);
        float y0f = floorf(py), x0f = floorf(px);
        int y0 = (int)y0f, x0 = (int)x0f;
        int y1 = y0 + 1,   x1 = x0 + 1;
        float wy1 = py - y0f, wx1 = px - x0f;
        float wy0 = 1.f - wy1, wx0 = 1.f - wx1;
        bool vy0 = ((unsigned)y0 < (unsigned)H_);
        bool vy1 = ((unsigned)y1 < (unsigned)H_);
        bool vx0 = ((unsigned)x0 < (unsigned)W_);
        bool vx1 = ((unsigned)x1 < (unsigned)W_);
        int cy0 = min(max(y0, 0), H_ - 1);
        int cy1 = min(max(y1, 0), H_ - 1);
        int cx0 = min(max(x0, 0), W_ - 1);
        int cx1 = min(max(x1, 0), W_ - 1);
        float b00 = wy0 * wx0 * ((vy0 && vx0) ? mk : 0.f);
        float b01 = wy0 * wx1 * ((vy0 && vx1) ? mk : 0.f);
        float b10 = wy1 * wx0 * ((vy1 && vx0) ? mk : 0.f);
        float b11 = wy1 * wx1 * ((vy1 && vx1) ? mk : 0.f);

        const float* p00 = xb + ((size_t)cy0 * W_ + cx0) * C_ + c0;
        const float* p01 = xb + ((size_t)cy0 * W_ + cx1) * C_ + c0;
        const float* p10 = xb + ((size_t)cy1 * W_ + cx0) * C_ + c0;
        const float* p11 = xb + ((size_t)cy1 * W_ + cx1) * C_ + c0;

#pragma unroll
        for (int q = 0; q < 4; q++) {
            float4 v00 = *(const float4*)(p00 + 4 * q);
            float4 v01 = *(const float4*)(p01 + 4 * q);
            float4 v10 = *(const float4*)(p10 + 4 * q);
            float4 v11 = *(const float4*)(p11 + 4 * q);
            float sx = b00 * v00.x + b01 * v01.x + b10 * v10.x + b11 * v11.x;
            float sy = b00 * v00.y + b01 * v01.y + b10 * v10.y + b11 * v11.y;
            float sz = b00 * v00.z + b01 * v01.z + b10 * v10.z + b11 * v11.z;
            float sw = b00 * v00.w + b01 * v01.w + b10 * v10.w + b11 * v11.w;
            acc[4*q+0] += wl[(c0 + 4*q + 0) * 9 + k] * sx;
            acc[4*q+1] += wl[(c0 + 4*q + 1) * 9 + k] * sy;
            acc[4*q+2] += wl[(c0 + 4*q + 2) * 9 + k] * sz;
            acc[4*q+3] += wl[(c0 + 4*q + 3) * 9 + k] * sw;
        }
    }

    float* op = out_pre + ((size_t)b * C_ + c0) * HW_ + hw;
#pragma unroll
    for (int c = 0; c < 16; c++) op[c * HW_] = acc[c] + bl[c0 + c];
}

// ---------------------------------------------------------------------------
// K4: per-(b,group) mean / rstd. One 1024-thread block per (b*32+g).
// ---------------------------------------------------------------------------
__global__ __launch_bounds__(1024) void k4_stats(const float* __restrict__ out_pre,
                                                 float* __restrict__ stats) {
    int bg = blockIdx.x;
    const float4* p = (const float4*)(out_pre + (size_t)bg * 2 * HW_);
    float s = 0.f, ss = 0.f;
    for (int i = threadIdx.x; i < 2 * HW_ / 4; i += 1024) {
        float4 v = p[i];
        s  += v.x + v.y + v.z + v.w;
        ss += v.x * v.x + v.y * v.y + v.z * v.z + v.w * v.w;
    }
#pragma unroll
    for (int m = 1; m < 64; m <<= 1) {
        s  += __shfl_xor(s, m);
        ss += __shfl_xor(ss, m);
    }
    __shared__ float ls[32];
    int lane = threadIdx.x & 63, wid = threadIdx.x >> 6;
    if (lane == 0) { ls[wid] = s; ls[16 + wid] = ss; }
    __syncthreads();
    if (threadIdx.x == 0) {
        float S = 0.f, SS = 0.f;
#pragma unroll
        for (int i = 0; i < 16; i++) { S += ls[i]; SS += ls[16 + i]; }
        const float inv = 1.f / (2.f * HW_);
        float mean = S * inv;
        float var  = SS * inv - mean * mean;
        stats[bg * 2]     = mean;
        stats[bg * 2 + 1] = rsqrtf(var + 1e-5f);
    }
}

// ---------------------------------------------------------------------------
// K5: normalize + gamma/beta + exact GELU -> d_out (float4)
// ---------------------------------------------------------------------------
__global__ __launch_bounds__(256) void k5_norm_gelu(const float* __restrict__ out_pre,
                                                    const float* __restrict__ stats,
                                                    const float* __restrict__ gamma,
                                                    const float* __restrict__ beta,
                                                    float* __restrict__ out) {
    int i = blockIdx.x * 256 + threadIdx.x;
    int e = i << 2;
    int c = (e >> 14) & (C_ - 1);
    int b = e >> 20;
    int bg = b * GROUPS_ + (c >> 1);
    float mean = stats[bg * 2];
    float rstd = stats[bg * 2 + 1];
    float ga = gamma[c] * rstd;
    float be = beta[c] - mean * ga;
    float4 v = ((const float4*)out_pre)[i];
    float4 r;
    float t;
    t = v.x * ga + be; r.x = 0.5f * t * (1.f + erff(t * 0.70710678118654752f));
    t = v.y * ga + be; r.y = 0.5f * t * (1.f + erff(t * 0.70710678118654752f));
    t = v.z * ga + be; r.z = 0.5f * t * (1.f + erff(t * 0.70710678118654752f));
    t = v.w * ga + be; r.w = 0.5f * t * (1.f + erff(t * 0.70710678118654752f));
    ((float4*)out)[i] = r;
}

// ---------------------------------------------------------------------------
extern "C" void kernel_launch(void* const* d_in, const int* in_sizes, int n_in,
                              void* d_out, int out_size, void* d_ws, size_t ws_size,
                              hipStream_t stream) {
    const float* x       = (const float*)d_in[0];
    const float* w_off1  = (const float*)d_in[1];
    const float* w_off2  = (const float*)d_in[2];
    const float* w_mask1 = (const float*)d_in[3];
    const float* w_mask2 = (const float*)d_in[4];
    const float* weight  = (const float*)d_in[5];
    const float* bias    = (const float*)d_in[6];
    const float* gamma   = (const float*)d_in[7];
    const float* beta    = (const float*)d_in[8];
    float* out = (float*)d_out;

    char* ws = (char*)d_ws;
    size_t o = 0;
    short* w1_hi = (short*)(ws + o); o += 8192 * 2;
    short* w1_lo = (short*)(ws + o); o += 8192 * 2;
    short* wo_hi = (short*)(ws + o); o += 32 * 576 * 2;
    short* wo_lo = (short*)(ws + o); o += 32 * 576 * 2;
    short* wm_hi = (short*)(ws + o); o += 16 * 576 * 2;
    short* wm_lo = (short*)(ws + o); o += 16 * 576 * 2;
    o = (o + 255) & ~(size_t)255;
    short* t1b     = (short*)(ws + o); o += (size_t)NPIX_ * 64 * 2;
    short* t2b     = (short*)(ws + o); o += (size_t)NPIX_ * 64 * 2;
    float* xt      = (float*)(ws + o); o += (size_t)NPIX_ * 64 * 4;
    float* offmask = (float*)(ws + o); o += (size_t)NPIX_ * 32 * 4;
    float* out_pre = (float*)(ws + o); o += (size_t)NPIX_ * 64 * 4;
    float* stats   = (float*)(ws + o); o += 256 * 4;

    hipLaunchKernelGGL(k0_prep, dim3(72), dim3(256), 0, stream,
                       w_off1, w_mask1, w_off2, w_mask2,
                       w1_hi, w1_lo, wo_hi, wo_lo, wm_hi, wm_lo);
    hipLaunchKernelGGL(k1_mfma, dim3(NPIX_ / 128), dim3(256), 0, stream,
                       x, w1_hi, w1_lo, t1b, t2b, xt);
    hipLaunchKernelGGL(k2_mfma, dim3(NPIX_ / 128), dim3(256), 0, stream,
                       t1b, t2b, wo_hi, wo_lo, wm_hi, wm_lo, offmask);
    hipLaunchKernelGGL(k3_deform, dim3(NPIX_ * 4 / 256), dim3(256), 0, stream,
                       xt, offmask, weight, bias, out_pre);
    hipLaunchKernelGGL(k4_stats, dim3(B_ * GROUPS_), dim3(1024), 0, stream,
                       out_pre, stats);
    hipLaunchKernelGGL(k5_norm_gelu, dim3(NPIX_ * 64 / 4 / 256), dim3(256), 0, stream,
                       out_pre, stats, gamma, beta, out);
}

// Round 4
// 169.312 us; speedup vs baseline: 2.3221x; 1.2740x over previous
//
#include <hip/hip_runtime.h>
#include <math.h>

#define B_  4
#define C_  64
#define H_  128
#define W_  128
#define HW_ (H_*W_)          // 16384
#define NPIX_ (B_*HW_)       // 65536
#define GROUPS_ 32

typedef __attribute__((ext_vector_type(8))) short short8;
typedef __attribute__((ext_vector_type(4))) float f32x4;

__device__ inline short f2bf_rne(float f) {
    unsigned u = __float_as_uint(f);
    unsigned r = (u + 0x7FFFu + ((u >> 16) & 1u)) >> 16;
    return (short)r;
}
__device__ inline float bf2f(short h) {
    return __uint_as_float(((unsigned)(unsigned short)h) << 16);
}

// ---------------------------------------------------------------------------
// K0: weight prep (bf16 hi/lo splits, transposed layouts for MFMA B-operands)
// ---------------------------------------------------------------------------
__global__ void k0_prep(const float* __restrict__ w_off1, const float* __restrict__ w_mask1,
                        const float* __restrict__ w_off2, const float* __restrict__ w_mask2,
                        short* __restrict__ w1_hi, short* __restrict__ w1_lo,
                        short* __restrict__ wo_hi, short* __restrict__ wo_lo,
                        short* __restrict__ wm_hi, short* __restrict__ wm_lo) {
    int i = blockIdx.x * 256 + threadIdx.x;
    if (i < 8192) {
        int co = i >> 6, ci = i & 63;
        float v = (co < 64) ? w_off1[co * 64 + ci] : w_mask1[(co - 64) * 64 + ci];
        short h = f2bf_rne(v);
        w1_hi[i] = h;
        w1_lo[i] = f2bf_rne(v - bf2f(h));
    }
    if (i < 32 * 576) {
        int cout = i / 576, r = i % 576;
        int pos = r >> 6, ci = r & 63;
        float v = (cout < 18) ? w_off2[(cout * 64 + ci) * 9 + pos] : 0.f;
        short h = f2bf_rne(v);
        wo_hi[i] = h;
        wo_lo[i] = f2bf_rne(v - bf2f(h));
    }
    if (i < 16 * 576) {
        int cout = i / 576, r = i % 576;
        int pos = r >> 6, ci = r & 63;
        float v = (cout < 9) ? w_mask2[(cout * 64 + ci) * 9 + pos] : 0.f;
        short h = f2bf_rne(v);
        wm_hi[i] = h;
        wm_lo[i] = f2bf_rne(v - bf2f(h));
    }
}

// ---------------------------------------------------------------------------
// K1: dual 1x1 conv via MFMA. Also emits xtb = bf16 NHWC copy of x (the A
// fragments themselves) for k3's gathers.
// ---------------------------------------------------------------------------
__global__ __launch_bounds__(256) void k1_mfma(const float* __restrict__ x,
                                               const short* __restrict__ w1_hi,
                                               const short* __restrict__ w1_lo,
                                               short* __restrict__ t1b,
                                               short* __restrict__ t2b,
                                               short* __restrict__ xtb) {
    int l   = threadIdx.x & 63;
    int wv  = threadIdx.x >> 6;
    int row = l >> 4, col = l & 15;
    int p0  = blockIdx.x * 128 + wv * 32;     // wave's pixel base
    int b   = p0 >> 14;
    int hw  = p0 & (HW_ - 1);
    const float* xb = x + (size_t)b * C_ * HW_ + hw;

    short8 afr[2][2];
#pragma unroll
    for (int mt = 0; mt < 2; mt++) {
        int pl = mt * 16 + col;               // lane's local pixel (A row m)
#pragma unroll
        for (int kb = 0; kb < 2; kb++) {
            int ci0 = kb * 32 + row * 8;      // A col k base
            float xv[8];
#pragma unroll
            for (int j = 0; j < 8; j++) xv[j] = xb[(ci0 + j) * HW_ + pl];
            short8 a;
#pragma unroll
            for (int j = 0; j < 8; j++) a[j] = f2bf_rne(xv[j]);
            afr[mt][kb] = a;
            union { short8 s; uint4 u; } cv2; cv2.s = a;
            *(uint4*)(xtb + ((size_t)(p0 + pl)) * 64 + ci0) = cv2.u;
        }
    }

    for (int nt = 0; nt < 8; nt++) {
        int co = nt * 16 + col;               // B col n
        union { uint4 u; short8 s; } cv;
        short8 bh[2], bl[2];
        const short* ph = w1_hi + (size_t)co * 64 + row * 8;
        const short* pl_ = w1_lo + (size_t)co * 64 + row * 8;
        cv.u = *(const uint4*)(ph);        bh[0] = cv.s;
        cv.u = *(const uint4*)(ph + 32);   bh[1] = cv.s;
        cv.u = *(const uint4*)(pl_);       bl[0] = cv.s;
        cv.u = *(const uint4*)(pl_ + 32);  bl[1] = cv.s;
        short* tgt = (co < 64) ? t1b : t2b;
        int c6 = co & 63;
#pragma unroll
        for (int mt = 0; mt < 2; mt++) {
            f32x4 acc = {0.f, 0.f, 0.f, 0.f};
            acc = __builtin_amdgcn_mfma_f32_16x16x32_bf16(afr[mt][0], bh[0], acc, 0, 0, 0);
            acc = __builtin_amdgcn_mfma_f32_16x16x32_bf16(afr[mt][0], bl[0], acc, 0, 0, 0);
            acc = __builtin_amdgcn_mfma_f32_16x16x32_bf16(afr[mt][1], bh[1], acc, 0, 0, 0);
            acc = __builtin_amdgcn_mfma_f32_16x16x32_bf16(afr[mt][1], bl[1], acc, 0, 0, 0);
#pragma unroll
            for (int r = 0; r < 4; r++) {
                int p = p0 + mt * 16 + row * 4 + r;
                tgt[(size_t)p * 64 + c6] = f2bf_rne(acc[r]);
            }
        }
    }
}

// ---------------------------------------------------------------------------
// K2: dual 3x3 conv via MFMA, K = 9pos x 64ci (pos-major), NHWC bf16 inputs.
// Output row offmask[pix][32]: [0..17]=off, [18..26]=mask(sigmoid).
// ---------------------------------------------------------------------------
__global__ __launch_bounds__(256) void k2_mfma(const short* __restrict__ t1b,
                                               const short* __restrict__ t2b,
                                               const short* __restrict__ wo_hi,
                                               const short* __restrict__ wo_lo,
                                               const short* __restrict__ wm_hi,
                                               const short* __restrict__ wm_lo,
                                               float* __restrict__ offmask) {
    int l   = threadIdx.x & 63;
    int wv  = threadIdx.x >> 6;
    int row = l >> 4, col = l & 15;
    int blk = blockIdx.x;
    int h   = blk & 127;                       // image row (blocks = one row each)
    int p0  = blk * 128;                       // global pixel base of this row
    int w0  = wv * 32;                         // wave's w-range [w0, w0+32)

    f32x4 aco[2][2] = {{{0.f,0.f,0.f,0.f},{0.f,0.f,0.f,0.f}},
                       {{0.f,0.f,0.f,0.f},{0.f,0.f,0.f,0.f}}};
    f32x4 acm[2]    = {{0.f,0.f,0.f,0.f},{0.f,0.f,0.f,0.f}};

    for (int kb = 0; kb < 18; kb++) {
        int pos = kb >> 1;
        int dy = pos / 3 - 1, dx = pos % 3 - 1;
        int ci0 = (kb & 1) * 32 + row * 8;
        int koff = pos * 64 + ci0;
        union { uint4 u; short8 s; } cv;
        short8 boh0, boh1, bol0, bol1, bmh, bml;
        cv.u = *(const uint4*)(wo_hi + (size_t)col * 576 + koff);        boh0 = cv.s;
        cv.u = *(const uint4*)(wo_hi + (size_t)(col + 16) * 576 + koff); boh1 = cv.s;
        cv.u = *(const uint4*)(wo_lo + (size_t)col * 576 + koff);        bol0 = cv.s;
        cv.u = *(const uint4*)(wo_lo + (size_t)(col + 16) * 576 + koff); bol1 = cv.s;
        cv.u = *(const uint4*)(wm_hi + (size_t)col * 576 + koff);        bmh  = cv.s;
        cv.u = *(const uint4*)(wm_lo + (size_t)col * 576 + koff);        bml  = cv.s;
#pragma unroll
        for (int mt = 0; mt < 2; mt++) {
            int w = w0 + mt * 16 + col;
            bool valid = ((unsigned)(h + dy) < 128u) && ((unsigned)(w + dx) < 128u);
            int ps = p0 + w + dy * 128 + dx;    // shifted global pixel
            short8 a1 = {0,0,0,0,0,0,0,0};
            short8 a2 = {0,0,0,0,0,0,0,0};
            if (valid) {
                cv.u = *(const uint4*)(t1b + (size_t)ps * 64 + ci0); a1 = cv.s;
                cv.u = *(const uint4*)(t2b + (size_t)ps * 64 + ci0); a2 = cv.s;
            }
            aco[mt][0] = __builtin_amdgcn_mfma_f32_16x16x32_bf16(a1, boh0, aco[mt][0], 0, 0, 0);
            aco[mt][0] = __builtin_amdgcn_mfma_f32_16x16x32_bf16(a1, bol0, aco[mt][0], 0, 0, 0);
            aco[mt][1] = __builtin_amdgcn_mfma_f32_16x16x32_bf16(a1, boh1, aco[mt][1], 0, 0, 0);
            aco[mt][1] = __builtin_amdgcn_mfma_f32_16x16x32_bf16(a1, bol1, aco[mt][1], 0, 0, 0);
            acm[mt]    = __builtin_amdgcn_mfma_f32_16x16x32_bf16(a2, bmh,  acm[mt],    0, 0, 0);
            acm[mt]    = __builtin_amdgcn_mfma_f32_16x16x32_bf16(a2, bml,  acm[mt],    0, 0, 0);
        }
    }

#pragma unroll
    for (int mt = 0; mt < 2; mt++) {
#pragma unroll
        for (int r = 0; r < 4; r++) {
            int p = p0 + w0 + mt * 16 + row * 4 + r;
            float* om = offmask + (size_t)p * 32;
            om[col] = aco[mt][0][r];
            if (col < 2) om[16 + col] = aco[mt][1][r];
            if (col < 9) om[18 + col] = 1.f / (1.f + expf(-acm[mt][r]));
        }
    }
}

// ---------------------------------------------------------------------------
// K3: deformable bilinear gather + einsum + bias -> out_pre (NCHW).
// bf16 NHWC gathers (half the bytes + half the load instructions vs fp32).
// XCD-band swizzle: block i -> XCD i&7 (round-robin heuristic); XCD x owns
// rows [16x,16x+16) of every image -> per-XCD working set ~1.2 MB << 4 MB L2.
// 4 threads/pixel, 16 channels each.
// ---------------------------------------------------------------------------
__global__ __launch_bounds__(256) void k3_deform(const short* __restrict__ xtb,
                                                 const float* __restrict__ offmask,
                                                 const float* __restrict__ weight,
                                                 const float* __restrict__ bias,
                                                 float* __restrict__ out_pre) {
    __shared__ float wl[C_ * 9];
    __shared__ float bl[C_];
    for (int i = threadIdx.x; i < C_ * 9; i += 256) wl[i] = weight[i];
    if (threadIdx.x < C_) bl[threadIdx.x] = bias[threadIdx.x];
    __syncthreads();

    int blk   = blockIdx.x;              // 1024 blocks, 64 pixels each
    int xcd   = blk & 7;
    int slot  = blk >> 3;                // 0..127
    int b     = slot >> 5;               // image
    int r     = (slot & 31) >> 1;        // row within band
    int hrow  = slot & 1;                // half-row
    int h     = xcd * 16 + r;
    int pl    = threadIdx.x >> 2;        // 0..63
    int chunk = threadIdx.x & 3;
    int c0    = chunk * 16;
    int w     = hrow * 64 + pl;
    int hw    = h * W_ + w;
    int P     = b * HW_ + hw;

    float acc[16];
#pragma unroll
    for (int i = 0; i < 16; i++) acc[i] = 0.f;

    const float* po = offmask + (size_t)P * 32;
    const short* xb = xtb + (size_t)b * HW_ * 64;

    for (int k = 0; k < 9; k++) {
        float offy = po[2 * k];
        float offx = po[2 * k + 1];
        float mk   = po[18 + k];
        float py = offy + (float)h + (float)(k / 3 - 1);
        float px = offx + (float)w + (float)(k % 3 - 1);
        float y0f = floorf(py), x0f = floorf(px);
        int y0 = (int)y0f, x0 = (int)x0f;
        int y1 = y0 + 1,   x1 = x0 + 1;
        float wy1 = py - y0f, wx1 = px - x0f;
        float wy0 = 1.f - wy1, wx0 = 1.f - wx1;
        bool vy0 = ((unsigned)y0 < (unsigned)H_);
        bool vy1 = ((unsigned)y1 < (unsigned)H_);
        bool vx0 = ((unsigned)x0 < (unsigned)W_);
        bool vx1 = ((unsigned)x1 < (unsigned)W_);
        int cy0 = min(max(y0, 0), H_ - 1);
        int cy1 = min(max(y1, 0), H_ - 1);
        int cx0 = min(max(x0, 0), W_ - 1);
        int cx1 = min(max(x1, 0), W_ - 1);
        float b00 = wy0 * wx0 * ((vy0 && vx0) ? mk : 0.f);
        float b01 = wy0 * wx1 * ((vy0 && vx1) ? mk : 0.f);
        float b10 = wy1 * wx0 * ((vy1 && vx0) ? mk : 0.f);
        float b11 = wy1 * wx1 * ((vy1 && vx1) ? mk : 0.f);

        const short* p00 = xb + ((size_t)cy0 * W_ + cx0) * 64 + c0;
        const short* p01 = xb + ((size_t)cy0 * W_ + cx1) * 64 + c0;
        const short* p10 = xb + ((size_t)cy1 * W_ + cx0) * 64 + c0;
        const short* p11 = xb + ((size_t)cy1 * W_ + cx1) * 64 + c0;

#pragma unroll
        for (int half = 0; half < 2; half++) {
            uint4 u00 = *(const uint4*)(p00 + 8 * half);
            uint4 u01 = *(const uint4*)(p01 + 8 * half);
            uint4 u10 = *(const uint4*)(p10 + 8 * half);
            uint4 u11 = *(const uint4*)(p11 + 8 * half);
            unsigned a00[4] = {u00.x, u00.y, u00.z, u00.w};
            unsigned a01[4] = {u01.x, u01.y, u01.z, u01.w};
            unsigned a10[4] = {u10.x, u10.y, u10.z, u10.w};
            unsigned a11[4] = {u11.x, u11.y, u11.z, u11.w};
#pragma unroll
            for (int d = 0; d < 4; d++) {
                float s_lo = b00 * __uint_as_float(a00[d] << 16)
                           + b01 * __uint_as_float(a01[d] << 16)
                           + b10 * __uint_as_float(a10[d] << 16)
                           + b11 * __uint_as_float(a11[d] << 16);
                float s_hi = b00 * __uint_as_float(a00[d] & 0xFFFF0000u)
                           + b01 * __uint_as_float(a01[d] & 0xFFFF0000u)
                           + b10 * __uint_as_float(a10[d] & 0xFFFF0000u)
                           + b11 * __uint_as_float(a11[d] & 0xFFFF0000u);
                int c = 8 * half + 2 * d;
                acc[c]     += wl[(c0 + c) * 9 + k] * s_lo;
                acc[c + 1] += wl[(c0 + c + 1) * 9 + k] * s_hi;
            }
        }
    }

    float* op = out_pre + ((size_t)b * C_ + c0) * HW_ + hw;
#pragma unroll
    for (int c = 0; c < 16; c++) op[c * HW_] = acc[c] + bl[c0 + c];
}

// ---------------------------------------------------------------------------
// K4: per-(b,group) mean / rstd. One 1024-thread block per (b*32+g).
// ---------------------------------------------------------------------------
__global__ __launch_bounds__(1024) void k4_stats(const float* __restrict__ out_pre,
                                                 float* __restrict__ stats) {
    int bg = blockIdx.x;
    const float4* p = (const float4*)(out_pre + (size_t)bg * 2 * HW_);
    float s = 0.f, ss = 0.f;
    for (int i = threadIdx.x; i < 2 * HW_ / 4; i += 1024) {
        float4 v = p[i];
        s  += v.x + v.y + v.z + v.w;
        ss += v.x * v.x + v.y * v.y + v.z * v.z + v.w * v.w;
    }
#pragma unroll
    for (int m = 1; m < 64; m <<= 1) {
        s  += __shfl_xor(s, m);
        ss += __shfl_xor(ss, m);
    }
    __shared__ float ls[32];
    int lane = threadIdx.x & 63, wid = threadIdx.x >> 6;
    if (lane == 0) { ls[wid] = s; ls[16 + wid] = ss; }
    __syncthreads();
    if (threadIdx.x == 0) {
        float S = 0.f, SS = 0.f;
#pragma unroll
        for (int i = 0; i < 16; i++) { S += ls[i]; SS += ls[16 + i]; }
        const float inv = 1.f / (2.f * HW_);
        float mean = S * inv;
        float var  = SS * inv - mean * mean;
        stats[bg * 2]     = mean;
        stats[bg * 2 + 1] = rsqrtf(var + 1e-5f);
    }
}

// ---------------------------------------------------------------------------
// K5: normalize + gamma/beta + exact GELU -> d_out (float4)
// ---------------------------------------------------------------------------
__global__ __launch_bounds__(256) void k5_norm_gelu(const float* __restrict__ out_pre,
                                                    const float* __restrict__ stats,
                                                    const float* __restrict__ gamma,
                                                    const float* __restrict__ beta,
                                                    float* __restrict__ out) {
    int i = blockIdx.x * 256 + threadIdx.x;
    int e = i << 2;
    int c = (e >> 14) & (C_ - 1);
    int b = e >> 20;
    int bg = b * GROUPS_ + (c >> 1);
    float mean = stats[bg * 2];
    float rstd = stats[bg * 2 + 1];
    float ga = gamma[c] * rstd;
    float be = beta[c] - mean * ga;
    float4 v = ((const float4*)out_pre)[i];
    float4 r;
    float t;
    t = v.x * ga + be; r.x = 0.5f * t * (1.f + erff(t * 0.70710678118654752f));
    t = v.y * ga + be; r.y = 0.5f * t * (1.f + erff(t * 0.70710678118654752f));
    t = v.z * ga + be; r.z = 0.5f * t * (1.f + erff(t * 0.70710678118654752f));
    t = v.w * ga + be; r.w = 0.5f * t * (1.f + erff(t * 0.70710678118654752f));
    ((float4*)out)[i] = r;
}

// ---------------------------------------------------------------------------
extern "C" void kernel_launch(void* const* d_in, const int* in_sizes, int n_in,
                              void* d_out, int out_size, void* d_ws, size_t ws_size,
                              hipStream_t stream) {
    const float* x       = (const float*)d_in[0];
    const float* w_off1  = (const float*)d_in[1];
    const float* w_off2  = (const float*)d_in[2];
    const float* w_mask1 = (const float*)d_in[3];
    const float* w_mask2 = (const float*)d_in[4];
    const float* weight  = (const float*)d_in[5];
    const float* bias    = (const float*)d_in[6];
    const float* gamma   = (const float*)d_in[7];
    const float* beta    = (const float*)d_in[8];
    float* out = (float*)d_out;

    char* ws = (char*)d_ws;
    size_t o = 0;
    short* w1_hi = (short*)(ws + o); o += 8192 * 2;
    short* w1_lo = (short*)(ws + o); o += 8192 * 2;
    short* wo_hi = (short*)(ws + o); o += 32 * 576 * 2;
    short* wo_lo = (short*)(ws + o); o += 32 * 576 * 2;
    short* wm_hi = (short*)(ws + o); o += 16 * 576 * 2;
    short* wm_lo = (short*)(ws + o); o += 16 * 576 * 2;
    o = (o + 255) & ~(size_t)255;
    short* t1b     = (short*)(ws + o); o += (size_t)NPIX_ * 64 * 2;
    short* t2b     = (short*)(ws + o); o += (size_t)NPIX_ * 64 * 2;
    short* xtb     = (short*)(ws + o); o += (size_t)NPIX_ * 64 * 2;
    float* offmask = (float*)(ws + o); o += (size_t)NPIX_ * 32 * 4;
    float* out_pre = (float*)(ws + o); o += (size_t)NPIX_ * 64 * 4;
    float* stats   = (float*)(ws + o); o += 256 * 4;

    hipLaunchKernelGGL(k0_prep, dim3(72), dim3(256), 0, stream,
                       w_off1, w_mask1, w_off2, w_mask2,
                       w1_hi, w1_lo, wo_hi, wo_lo, wm_hi, wm_lo);
    hipLaunchKernelGGL(k1_mfma, dim3(NPIX_ / 128), dim3(256), 0, stream,
                       x, w1_hi, w1_lo, t1b, t2b, xtb);
    hipLaunchKernelGGL(k2_mfma, dim3(NPIX_ / 128), dim3(256), 0, stream,
                       t1b, t2b, wo_hi, wo_lo, wm_hi, wm_lo, offmask);
    hipLaunchKernelGGL(k3_deform, dim3(NPIX_ / 64), dim3(256), 0, stream,
                       xtb, offmask, weight, bias, out_pre);
    hipLaunchKernelGGL(k4_stats, dim3(B_ * GROUPS_), dim3(1024), 0, stream,
                       out_pre, stats);
    hipLaunchKernelGGL(k5_norm_gelu, dim3(NPIX_ * 64 / 4 / 256), dim3(256), 0, stream,
                       out_pre, stats, gamma, beta, out);
}